// Round 11
// baseline (1582.390 us; speedup 1.0000x reference)
//
#include <hip/hip_runtime.h>
#include <cstdint>
#include <cstddef>

#define BNR 16384   // b*n rows
#define C   512     // feature dim
#define M   8192    // codebook size
#define BM  256
#define BN  256
#define BK  32
#define NCH 16      // K chunks = C/BK
#define NSETS 32    // column blocks (8192/256)

// tiled operand layout: [block256][chunk16][kb4][row256][8 u16]
// per (block,chunk) tile = 1024 units of 16B = 16 KiB; per block = 128 KiB.
#define TILE_U16   8192      // u16 per (block,chunk) tile
#define BLOCK_U16  131072    // u16 per block (16 chunks)

typedef float f32x4 __attribute__((ext_vector_type(4)));
typedef _Float16 f16x8 __attribute__((ext_vector_type(8)));
typedef unsigned short u16;

static __device__ __forceinline__ u16 h_bits(_Float16 h) {
    union { _Float16 h; u16 u; } x; x.h = h; return x.u;
}
static __device__ __forceinline__ void gl_lds16(const void* g, void* l) {
    __builtin_amdgcn_global_load_lds(
        (const __attribute__((address_space(1))) void*)g,
        (__attribute__((address_space(3))) void*)l, 16, 0, 0);
}

// ---------------- ||k||^2 per codebook row (exact fp32) ----------------
__global__ void knorm_k(const float* __restrict__ emb, float* __restrict__ knorm) {
    int gw   = (blockIdx.x * blockDim.x + threadIdx.x) >> 6;
    int lane = threadIdx.x & 63;
    int nw   = (gridDim.x * blockDim.x) >> 6;
    for (int row = gw; row < M; row += nw) {
        const float4* p = (const float4*)(emb + (size_t)row * C);
        float s = 0.f;
#pragma unroll
        for (int j = 0; j < 2; ++j) {
            float4 v = p[lane + 64 * j];
            s += v.x * v.x + v.y * v.y + v.z * v.z + v.w * v.w;
        }
#pragma unroll
        for (int o = 32; o > 0; o >>= 1) s += __shfl_down(s, o, 64);
        if (lane == 0) knorm[row] = s;
    }
}

// ---------------- fp32 -> fp16 hi, written in TILED layout ----------------
// One thread per 16B output unit, OUTPUT-linear (coalesced HBM writes;
// the 16B-scattered reads are absorbed by L2).
__global__ void cvt_tile_k(const float* __restrict__ in, u16* __restrict__ outp) {
    int o = blockIdx.x * 256 + threadIdx.x;
    int q = o & 1023, kb = q >> 8, row = q & 255;
    int c = (o >> 10) & 15, blk = o >> 14;
    int grow = blk * 256 + row;
    int k0 = c * BK + kb * 8;
    const float4* src = (const float4*)(in + (size_t)grow * C + k0);
    float4 a = src[0], b = src[1];
    u16 v[8] = { h_bits((_Float16)a.x), h_bits((_Float16)a.y),
                 h_bits((_Float16)a.z), h_bits((_Float16)a.w),
                 h_bits((_Float16)b.x), h_bits((_Float16)b.y),
                 h_bits((_Float16)b.z), h_bits((_Float16)b.w) };
    u16* dst = outp + (size_t)o * 8;
    *(ushort4*)(dst)     = *(ushort4*)(v);
    *(ushort4*)(dst + 4) = *(ushort4*)(v + 4);
}

// ---------------- MFMA distance GEMM + per-colblock top-2 ----------------
// 2048 blocks x 512 threads (8 waves, 2M x 4N, per-wave 128x64 = acc[8][4]).
// Double-buffered LDS (BK=32, 2 x 32 KiB = 64 KiB/block -> 2 BLOCKS/CU),
// T3 minimum 2-phase: STAGE(c+1) -> ds_read(c) -> MFMA -> vmcnt(0) -> barrier.
// Operands pre-tiled in global: STAGE is base + u*16B, fully coalesced;
// LDS lands in [kb][row][8] (conflict-free ds_read_b128).
__global__ __launch_bounds__(512, 4) void mfma_argmin_k(
    const u16* __restrict__ x2t, const u16* __restrict__ e2t,
    const float* __restrict__ knorm,
    float* __restrict__ pv1, int* __restrict__ pi1,
    float* __restrict__ pv2, int* __restrict__ pi2) {
    __shared__ __align__(16) u16 ldsA[2][4][256][8];   // 32 KiB
    __shared__ __align__(16) u16 ldsB[2][4][256][8];   // 32 KiB

    const int tid  = threadIdx.x;
    const int lane = tid & 63;
    const int w    = tid >> 6;          // 0..7
    const int wm   = w >> 2, wn = w & 3;
    const int g    = lane >> 4, r = lane & 15;

    // supertile XCD swizzle: XCD gets 4 supertiles of 8rb x 8cb.
    const int xk = blockIdx.x & 7, j = blockIdx.x >> 3;
    const int st = xk + 8 * (j >> 6);        // supertile 0..31
    const int p  = j & 63;
    const int rb = (st & 7) * 8 + (p & 7);   // 0..63
    const int cb = (st >> 3) * 8 + (p >> 3); // 0..31
    const int rowBase = rb * BM, colBase = cb * BN;

    f32x4 acc[8][4];
#pragma unroll
    for (int m = 0; m < 8; ++m)
#pragma unroll
        for (int n = 0; n < 4; ++n) acc[m][n] = (f32x4)(0.0f);

    const u16* aT = x2t + (size_t)rb * BLOCK_U16;
    const u16* bT = e2t + (size_t)cb * BLOCK_U16;

#define STAGE(buf, c)                                                          \
    {                                                                          \
        _Pragma("unroll")                                                      \
        for (int it = 0; it < 2; ++it) {                                       \
            int u = it * 512 + tid;                                            \
            gl_lds16(aT + (size_t)(c) * TILE_U16 + u * 8,                      \
                     &ldsA[buf][0][0][0] + u * 8);                             \
            gl_lds16(bT + (size_t)(c) * TILE_U16 + u * 8,                      \
                     &ldsB[buf][0][0][0] + u * 8);                             \
        }                                                                      \
    }

    // prologue: tile 0 staged and landed
    STAGE(0, 0);
    asm volatile("s_waitcnt vmcnt(0)" ::: "memory");
    __builtin_amdgcn_s_barrier();
    __builtin_amdgcn_sched_barrier(0);

#pragma unroll 1
    for (int c = 0; c < NCH; ++c) {
        const int buf = c & 1;
        if (c + 1 < NCH) STAGE(buf ^ 1, c + 1);   // other buffer: readers retired

        f16x8 a[8], b[4];
#pragma unroll
        for (int m = 0; m < 8; ++m)
            a[m] = *(const f16x8*)&ldsA[buf][g][wm * 128 + m * 16 + r][0];
#pragma unroll
        for (int n = 0; n < 4; ++n)
            b[n] = *(const f16x8*)&ldsB[buf][g][wn * 64 + n * 16 + r][0];

        __builtin_amdgcn_s_setprio(1);
#pragma unroll
        for (int m = 0; m < 8; ++m)
#pragma unroll
            for (int n = 0; n < 4; ++n)
                acc[m][n] = __builtin_amdgcn_mfma_f32_16x16x32_f16(
                    a[m], b[n], acc[m][n], 0, 0, 0);
        __builtin_amdgcn_s_setprio(0);
        __builtin_amdgcn_sched_barrier(0);

        // tile c+1 landed (own loads) -> barrier publishes all waves' DMA
        asm volatile("s_waitcnt vmcnt(0)" ::: "memory");
        __builtin_amdgcn_s_barrier();
        __builtin_amdgcn_sched_barrier(0);
    }
#undef STAGE

    // ---- epilogue: per-row top-2 over this block's 256 cols ----
    float kn[4];
#pragma unroll
    for (int n = 0; n < 4; ++n) kn[n] = knorm[colBase + wn * 64 + n * 16 + r];

    float* mv = (float*)&ldsA[0][0][0][0];        // [4 wn][256 row][2]
    int*   mi = (int*)(mv + 4 * 256 * 2);         // 8 KiB + 8 KiB

#pragma unroll
    for (int m = 0; m < 8; ++m) {
#pragma unroll
        for (int q = 0; q < 4; ++q) {
            float v1 = 3.0e38f, v2 = 3.0e38f;
            int   i1 = 0x7fffffff, i2 = 0x7fffffff;
#pragma unroll
            for (int n = 0; n < 4; ++n) {
                int col = colBase + wn * 64 + n * 16 + r;
                float d = fmaf(-2.0f, acc[m][n][q], kn[n]);
                if (d < v1 || (d == v1 && col < i1)) {
                    v2 = v1; i2 = i1; v1 = d; i1 = col;
                } else if (d < v2 || (d == v2 && col < i2)) {
                    v2 = d; i2 = col;
                }
            }
#pragma unroll
            for (int msk = 1; msk < 16; msk <<= 1) {
                float ov1 = __shfl_xor(v1, msk, 64);
                int   oi1 = __shfl_xor(i1, msk, 64);
                float ov2 = __shfl_xor(v2, msk, 64);
                int   oi2 = __shfl_xor(i2, msk, 64);
                bool ob = (ov1 < v1) || (ov1 == v1 && oi1 < i1);
                float nbv = ob ? ov1 : v1;  int nbi = ob ? oi1 : i1;
                float c1v = ob ? ov2 : v2;  int c1i = ob ? oi2 : i2;
                float c2v = ob ? v1 : ov1;  int c2i = ob ? i1 : oi1;
                bool cb2 = (c2v < c1v) || (c2v == c1v && c2i < c1i);
                v1 = nbv; i1 = nbi;
                v2 = cb2 ? c2v : c1v; i2 = cb2 ? c2i : c1i;
            }
            if (r == 0) {
                int lrow = wm * 128 + m * 16 + g * 4 + q;   // 0..255
                mv[(wn * 256 + lrow) * 2 + 0] = v1;
                mv[(wn * 256 + lrow) * 2 + 1] = v2;
                mi[(wn * 256 + lrow) * 2 + 0] = i1;
                mi[(wn * 256 + lrow) * 2 + 1] = i2;
            }
        }
    }
    __syncthreads();

    // merge 4 wn-waves' top-2 -> per-row top-2 over 256 cols
    if (tid < 256) {
        float V1 = 3.0e38f, V2 = 3.0e38f;
        int   I1 = 0x7fffffff, I2 = 0x7fffffff;
#pragma unroll
        for (int s = 0; s < 8; ++s) {
            float d = mv[((s >> 1) * 256 + tid) * 2 + (s & 1)];
            int   ci = mi[((s >> 1) * 256 + tid) * 2 + (s & 1)];
            if (d < V1 || (d == V1 && ci < I1)) {
                V2 = V1; I2 = I1; V1 = d; I1 = ci;
            } else if (d < V2 || (d == V2 && ci < I2)) {
                V2 = d; I2 = ci;
            }
        }
        size_t o = (size_t)cb * BNR + rowBase + tid;
        pv1[o] = V1; pi1[o] = I1;
        pv2[o] = V2; pi2[o] = I2;
    }
}

// ---------------- refine: top-8 by fp32 value, exact fp64 distances ----------------
__global__ void refine_k(const float* __restrict__ x, const float* __restrict__ emb,
                         const float* __restrict__ pv1, const int* __restrict__ pi1,
                         const float* __restrict__ pv2, const int* __restrict__ pi2,
                         float* __restrict__ out_idx) {
    int row  = blockIdx.x * 4 + (threadIdx.x >> 6);
    int lane = threadIdx.x & 63;
    float v; int idx;
    if (lane < NSETS) {
        v = pv1[(size_t)lane * BNR + row]; idx = pi1[(size_t)lane * BNR + row];
    } else {
        v = pv2[(size_t)(lane - NSETS) * BNR + row]; idx = pi2[(size_t)(lane - NSETS) * BNR + row];
    }
    int cand[8];
#pragma unroll
    for (int b = 0; b < 8; ++b) {
        float mvv = v; int mii = idx;
#pragma unroll
        for (int msk = 1; msk < 64; msk <<= 1) {
            float ov = __shfl_xor(mvv, msk, 64);
            int   oi = __shfl_xor(mii, msk, 64);
            if (ov < mvv || (ov == mvv && oi < mii)) { mvv = ov; mii = oi; }
        }
        cand[b] = mii;
        if (v == mvv && idx == mii) { v = 3.0e38f; idx = 0x7fffffff; }
    }
    int gid = lane >> 3, gl = lane & 7;
    int myc = cand[gid];
    const float* qp = x + (size_t)row * C;
    const float* kp = emb + (size_t)myc * C;
    double s = 0.0;
#pragma unroll 4
    for (int j = gl * 64; j < gl * 64 + 64; j += 4) {
        float4 q4 = *(const float4*)(qp + j);
        float4 k4 = *(const float4*)(kp + j);
        double d0 = (double)q4.x - (double)k4.x;
        double d1 = (double)q4.y - (double)k4.y;
        double d2 = (double)q4.z - (double)k4.z;
        double d3 = (double)q4.w - (double)k4.w;
        s += d0 * d0 + d1 * d1 + d2 * d2 + d3 * d3;
    }
    s += __shfl_xor(s, 1, 64);
    s += __shfl_xor(s, 2, 64);
    s += __shfl_xor(s, 4, 64);
    double dv = (gl == 0) ? s : 1.0e300;
    int    di = (gl == 0) ? myc : 0x7fffffff;
#pragma unroll
    for (int msk = 8; msk < 64; msk <<= 1) {
        double ov = __shfl_xor(dv, msk, 64);
        int    oi = __shfl_xor(di, msk, 64);
        if (ov < dv || (ov == dv && oi < di)) { dv = ov; di = oi; }
    }
    if (lane == 0) out_idx[row] = (float)di;
}

// ---------------- gather z_st + scatter onehot ones ----------------
__global__ void gather_k(const float* __restrict__ emb, const float* __restrict__ out_idx,
                         float* __restrict__ zst, float* __restrict__ onehot) {
    int row = blockIdx.x;
    int idx = (int)out_idx[row];
    const float4* src = (const float4*)(emb + (size_t)idx * C);
    float4* dst = (float4*)(zst + (size_t)row * C);
    dst[threadIdx.x] = src[threadIdx.x];
    if (threadIdx.x == 0) onehot[(size_t)row * M + idx] = 1.0f;
}

// ---------------- perplexity via LDS histogram ----------------
__global__ void perp_k(const float* __restrict__ out_idx, float* __restrict__ out_perp) {
    __shared__ int hist[M];
    __shared__ float red[256];
    int tid = threadIdx.x;
    for (int j = tid; j < M; j += 256) hist[j] = 0;
    __syncthreads();
    for (int j = tid; j < BNR; j += 256) atomicAdd(&hist[(int)out_idx[j]], 1);
    __syncthreads();
    float s = 0.f;
    for (int j = tid; j < M; j += 256) {
        float pb = (float)hist[j] * (1.0f / (float)BNR);
        s += pb * logf(pb + 1e-10f);
    }
    red[tid] = s; __syncthreads();
    for (int o = 128; o > 0; o >>= 1) {
        if (tid < o) red[tid] += red[tid + o];
        __syncthreads();
    }
    if (tid == 0) out_perp[0] = expf(-red[0]);
}

extern "C" void kernel_launch(void* const* d_in, const int* in_sizes, int n_in,
                              void* d_out, int out_size, void* d_ws, size_t ws_size,
                              hipStream_t stream) {
    const float* x   = (const float*)d_in[0];
    const float* emb = (const float*)d_in[1];

    float* out        = (float*)d_out;
    float* out_zst    = out;                              // 8388608
    float* out_idx    = out + (size_t)BNR * C;            // 16384
    float* out_onehot = out_idx + BNR;                    // 134217728
    float* out_perp   = out_onehot + (size_t)BNR * M;     // 1

    // scratch lives in the onehot region (memset afterwards): ~33 MiB used
    u16*   x2t   = (u16*)out_onehot;                      // 16 MiB (tiled)
    u16*   e2t   = x2t + (size_t)BNR * C;                 // 8 MiB  (tiled)
    float* knorm = (float*)(e2t + (size_t)M * C);
    float* pv1   = knorm + M;
    float* pv2   = pv1 + (size_t)NSETS * BNR;
    int*   pi1   = (int*)(pv2 + (size_t)NSETS * BNR);
    int*   pi2   = pi1 + (size_t)NSETS * BNR;

    cvt_tile_k<<<(BNR * C / 8) / 256, 256, 0, stream>>>(x, x2t);
    cvt_tile_k<<<(M * C / 8) / 256, 256, 0, stream>>>(emb, e2t);
    knorm_k<<<64, 256, 0, stream>>>(emb, knorm);
    mfma_argmin_k<<<(BNR / BM) * (M / BN), 512, 0, stream>>>(
        x2t, e2t, knorm, pv1, pi1, pv2, pi2);
    refine_k<<<BNR / 4, 256, 0, stream>>>(x, emb, pv1, pi1, pv2, pi2, out_idx);

    hipMemsetAsync(out_onehot, 0, (size_t)BNR * M * sizeof(float), stream);
    gather_k<<<BNR, 128, 0, stream>>>(emb, out_idx, out_zst, out_onehot);
    perp_k<<<1, 256, 0, stream>>>(out_idx, out_perp);
}

// Round 12
// 480.402 us; speedup vs baseline: 3.2939x; 3.2939x over previous
//
#include <hip/hip_runtime.h>
#include <cstdint>
#include <cstddef>

#define BNR 16384   // b*n rows
#define C   512     // feature dim
#define M   8192    // codebook size
#define BM  128
#define BN  128
#define BK  64
#define NCH 8       // K chunks = C/BK
#define NSETS 64    // column blocks (8192/128)

// tiled operand layout: [panel128][chunk8][kb8][row128][8 u16]
// per (panel,chunk) tile = 1024 units of 16B = 16 KiB; per panel = 128 KiB.
#define TILE_U16   8192      // u16 per (panel,chunk) tile
#define PANEL_U16  65536     // u16 per 128-row panel (8 chunks)

typedef float f32x4 __attribute__((ext_vector_type(4)));
typedef _Float16 f16x8 __attribute__((ext_vector_type(8)));
typedef unsigned short u16;

static __device__ __forceinline__ u16 h_bits(_Float16 h) {
    union { _Float16 h; u16 u; } x; x.h = h; return x.u;
}
static __device__ __forceinline__ void gl_lds16(const void* g, void* l) {
    __builtin_amdgcn_global_load_lds(
        (const __attribute__((address_space(1))) void*)g,
        (__attribute__((address_space(3))) void*)l, 16, 0, 0);
}

// ---------------- ||k||^2 per codebook row (exact fp32) ----------------
__global__ void knorm_k(const float* __restrict__ emb, float* __restrict__ knorm) {
    int gw   = (blockIdx.x * blockDim.x + threadIdx.x) >> 6;
    int lane = threadIdx.x & 63;
    int nw   = (gridDim.x * blockDim.x) >> 6;
    for (int row = gw; row < M; row += nw) {
        const float4* p = (const float4*)(emb + (size_t)row * C);
        float s = 0.f;
#pragma unroll
        for (int j = 0; j < 2; ++j) {
            float4 v = p[lane + 64 * j];
            s += v.x * v.x + v.y * v.y + v.z * v.z + v.w * v.w;
        }
#pragma unroll
        for (int o = 32; o > 0; o >>= 1) s += __shfl_down(s, o, 64);
        if (lane == 0) knorm[row] = s;
    }
}

// ---------------- fp32 -> fp16 hi, written in TILED layout ----------------
// One thread per 16B output unit, OUTPUT-linear (coalesced HBM writes).
// unit o: q=o&1023 -> kb=q>>7, row=q&127 ; chunk c=(o>>10)&7 ; panel=o>>13
__global__ void cvt_tile_k(const float* __restrict__ in, u16* __restrict__ outp) {
    int o = blockIdx.x * 256 + threadIdx.x;
    int q = o & 1023, kb = q >> 7, row = q & 127;
    int c = (o >> 10) & 7, pan = o >> 13;
    int grow = pan * BM + row;
    int k0 = c * BK + kb * 8;
    const float4* src = (const float4*)(in + (size_t)grow * C + k0);
    float4 a = src[0], b = src[1];
    u16 v[8] = { h_bits((_Float16)a.x), h_bits((_Float16)a.y),
                 h_bits((_Float16)a.z), h_bits((_Float16)a.w),
                 h_bits((_Float16)b.x), h_bits((_Float16)b.y),
                 h_bits((_Float16)b.z), h_bits((_Float16)b.w) };
    u16* dst = outp + (size_t)o * 8;
    *(ushort4*)(dst)     = *(ushort4*)(v);
    *(ushort4*)(dst + 4) = *(ushort4*)(v + 4);
}

// ---------------- MFMA distance GEMM + per-colblock top-2 ----------------
// m97 structure: 8192 blocks x 256 threads (4 waves, 2x2, 64x64/wave,
// acc[4][4]), single 32 KiB LDS buffer, 2 barriers per K-step, pre-tiled
// global operands -> gl_lds fully coalesced, LDS [kb][row][8] conflict-free.
// ~164 VGPR -> ~3 blocks/CU: inter-block overlap hides the barrier drain.
__global__ void mfma_argmin_k(
    const u16* __restrict__ x2t, const u16* __restrict__ e2t,
    const float* __restrict__ knorm,
    float* __restrict__ pv1, int* __restrict__ pi1,
    float* __restrict__ pv2, int* __restrict__ pi2) {
    __shared__ __align__(16) u16 ldsA[8][128][8];   // 16 KiB
    __shared__ __align__(16) u16 ldsB[8][128][8];   // 16 KiB

    const int tid  = threadIdx.x;
    const int lane = tid & 63;
    const int w    = tid >> 6;          // 0..3
    const int wm   = w >> 1, wn = w & 1;
    const int g    = lane >> 4, r = lane & 15;

    // bijective supertile XCD swizzle: supertile = 8rb x 8cb (64 blocks);
    // XCD gets 16 supertiles; concurrent window stays inside 4 MiB L2.
    const int xk = blockIdx.x & 7, j = blockIdx.x >> 3;
    const int stid = (j >> 6) * 8 + xk;      // 0..127
    const int p  = j & 63;
    const int rb = (stid & 15) * 8 + (p & 7);   // 0..127
    const int cb = (stid >> 4) * 8 + (p >> 3);  // 0..63
    const int rowBase = rb * BM, colBase = cb * BN;

    f32x4 acc[4][4];
#pragma unroll
    for (int m = 0; m < 4; ++m)
#pragma unroll
        for (int n = 0; n < 4; ++n) acc[m][n] = (f32x4)(0.0f);

    const u16* aT = x2t + (size_t)rb * PANEL_U16;
    const u16* bT = e2t + (size_t)cb * PANEL_U16;

#pragma unroll 1
    for (int c = 0; c < NCH; ++c) {
        if (c) __syncthreads();           // readers of previous tile done
#pragma unroll
        for (int it = 0; it < 4; ++it) {  // stage: 4 A-units + 4 B-units/thread
            int u = it * 256 + tid;
            gl_lds16(aT + (size_t)c * TILE_U16 + u * 8, (u16*)ldsA + u * 8);
            gl_lds16(bT + (size_t)c * TILE_U16 + u * 8, (u16*)ldsB + u * 8);
        }
        __syncthreads();                  // publishes DMA (vmcnt(0) implicit)

#pragma unroll
        for (int ks = 0; ks < 2; ++ks) {
            const int kb = ks * 4 + g;
            f16x8 a[4], b[4];
#pragma unroll
            for (int m = 0; m < 4; ++m)
                a[m] = *(const f16x8*)&ldsA[kb][wm * 64 + m * 16 + r][0];
#pragma unroll
            for (int n = 0; n < 4; ++n)
                b[n] = *(const f16x8*)&ldsB[kb][wn * 64 + n * 16 + r][0];
#pragma unroll
            for (int m = 0; m < 4; ++m)
#pragma unroll
                for (int n = 0; n < 4; ++n)
                    acc[m][n] = __builtin_amdgcn_mfma_f32_16x16x32_f16(
                        a[m], b[n], acc[m][n], 0, 0, 0);
        }
    }
    __syncthreads();   // last ds_reads retired before LDS reuse

    // ---- epilogue: per-row top-2 over this block's 128 cols ----
    float kn[4];
#pragma unroll
    for (int n = 0; n < 4; ++n) kn[n] = knorm[colBase + wn * 64 + n * 16 + r];

    float* mv = (float*)&ldsA[0][0][0];           // [2 wn][128 row][2]
    int*   mi = (int*)(mv + 2 * 128 * 2);         // 2 KiB + 2 KiB

#pragma unroll
    for (int m = 0; m < 4; ++m) {
#pragma unroll
        for (int q = 0; q < 4; ++q) {
            float v1 = 3.0e38f, v2 = 3.0e38f;
            int   i1 = 0x7fffffff, i2 = 0x7fffffff;
#pragma unroll
            for (int n = 0; n < 4; ++n) {
                int col = colBase + wn * 64 + n * 16 + r;
                float d = fmaf(-2.0f, acc[m][n][q], kn[n]);
                if (d < v1 || (d == v1 && col < i1)) {
                    v2 = v1; i2 = i1; v1 = d; i1 = col;
                } else if (d < v2 || (d == v2 && col < i2)) {
                    v2 = d; i2 = col;
                }
            }
#pragma unroll
            for (int msk = 1; msk < 16; msk <<= 1) {
                float ov1 = __shfl_xor(v1, msk, 64);
                int   oi1 = __shfl_xor(i1, msk, 64);
                float ov2 = __shfl_xor(v2, msk, 64);
                int   oi2 = __shfl_xor(i2, msk, 64);
                bool ob = (ov1 < v1) || (ov1 == v1 && oi1 < i1);
                float nbv = ob ? ov1 : v1;  int nbi = ob ? oi1 : i1;
                float c1v = ob ? ov2 : v2;  int c1i = ob ? oi2 : i2;
                float c2v = ob ? v1 : ov1;  int c2i = ob ? i1 : oi1;
                bool cb2 = (c2v < c1v) || (c2v == c1v && c2i < c1i);
                v1 = nbv; i1 = nbi;
                v2 = cb2 ? c2v : c1v; i2 = cb2 ? c2i : c1i;
            }
            if (r == 0) {
                int lrow = wm * 64 + m * 16 + g * 4 + q;   // 0..127
                mv[(wn * 128 + lrow) * 2 + 0] = v1;
                mv[(wn * 128 + lrow) * 2 + 1] = v2;
                mi[(wn * 128 + lrow) * 2 + 0] = i1;
                mi[(wn * 128 + lrow) * 2 + 1] = i2;
            }
        }
    }
    __syncthreads();

    // merge 2 wn-halves' top-2 -> per-row top-2 over 128 cols
    if (tid < 128) {
        float V1 = 3.0e38f, V2 = 3.0e38f;
        int   I1 = 0x7fffffff, I2 = 0x7fffffff;
#pragma unroll
        for (int s = 0; s < 4; ++s) {
            float d = mv[((s >> 1) * 128 + tid) * 2 + (s & 1)];
            int   ci = mi[((s >> 1) * 128 + tid) * 2 + (s & 1)];
            if (d < V1 || (d == V1 && ci < I1)) {
                V2 = V1; I2 = I1; V1 = d; I1 = ci;
            } else if (d < V2 || (d == V2 && ci < I2)) {
                V2 = d; I2 = ci;
            }
        }
        size_t o = (size_t)cb * BNR + rowBase + tid;
        pv1[o] = V1; pi1[o] = I1;
        pv2[o] = V2; pi2[o] = I2;
    }
}

// ---------------- refine: top-8 of 128 candidates, exact fp64 ----------------
// block 256 = 4 waves = 4 rows; lane l holds set l's {top1, top2}.
__global__ void refine_k(const float* __restrict__ x, const float* __restrict__ emb,
                         const float* __restrict__ pv1, const int* __restrict__ pi1,
                         const float* __restrict__ pv2, const int* __restrict__ pi2,
                         float* __restrict__ out_idx) {
    int row  = blockIdx.x * 4 + (threadIdx.x >> 6);
    int lane = threadIdx.x & 63;
    size_t off = (size_t)lane * BNR + row;
    float va = pv1[off]; int ia = pi1[off];
    float vb = pv2[off]; int ib = pi2[off];
    int cand[8];
#pragma unroll
    for (int b = 0; b < 8; ++b) {
        bool al = (va < vb) || (va == vb && ia < ib);
        float cv = al ? va : vb; int ci = al ? ia : ib;
#pragma unroll
        for (int msk = 1; msk < 64; msk <<= 1) {
            float ov = __shfl_xor(cv, msk, 64);
            int   oi = __shfl_xor(ci, msk, 64);
            if (ov < cv || (ov == cv && oi < ci)) { cv = ov; ci = oi; }
        }
        cand[b] = ci;
        // indices are globally unique -> invalidate by index
        if (ia == ci) va = 3.0e38f;
        else if (ib == ci) vb = 3.0e38f;
    }
    int gid = lane >> 3, gl = lane & 7;
    int myc = cand[gid];
    const float* qp = x + (size_t)row * C;
    const float* kp = emb + (size_t)myc * C;
    double s = 0.0;
#pragma unroll 4
    for (int j = gl * 64; j < gl * 64 + 64; j += 4) {
        float4 q4 = *(const float4*)(qp + j);
        float4 k4 = *(const float4*)(kp + j);
        double d0 = (double)q4.x - (double)k4.x;
        double d1 = (double)q4.y - (double)k4.y;
        double d2 = (double)q4.z - (double)k4.z;
        double d3 = (double)q4.w - (double)k4.w;
        s += d0 * d0 + d1 * d1 + d2 * d2 + d3 * d3;
    }
    s += __shfl_xor(s, 1, 64);
    s += __shfl_xor(s, 2, 64);
    s += __shfl_xor(s, 4, 64);
    double dv = (gl == 0) ? s : 1.0e300;
    int    di = (gl == 0) ? myc : 0x7fffffff;
#pragma unroll
    for (int msk = 8; msk < 64; msk <<= 1) {
        double ov = __shfl_xor(dv, msk, 64);
        int    oi = __shfl_xor(di, msk, 64);
        if (ov < dv || (ov == dv && oi < di)) { dv = ov; di = oi; }
    }
    if (lane == 0) out_idx[row] = (float)di;
}

// ---------------- gather z_st + scatter onehot ones ----------------
__global__ void gather_k(const float* __restrict__ emb, const float* __restrict__ out_idx,
                         float* __restrict__ zst, float* __restrict__ onehot) {
    int row = blockIdx.x;
    int idx = (int)out_idx[row];
    const float4* src = (const float4*)(emb + (size_t)idx * C);
    float4* dst = (float4*)(zst + (size_t)row * C);
    dst[threadIdx.x] = src[threadIdx.x];
    if (threadIdx.x == 0) onehot[(size_t)row * M + idx] = 1.0f;
}

// ---------------- perplexity via LDS histogram ----------------
__global__ void perp_k(const float* __restrict__ out_idx, float* __restrict__ out_perp) {
    __shared__ int hist[M];
    __shared__ float red[256];
    int tid = threadIdx.x;
    for (int j = tid; j < M; j += 256) hist[j] = 0;
    __syncthreads();
    for (int j = tid; j < BNR; j += 256) atomicAdd(&hist[(int)out_idx[j]], 1);
    __syncthreads();
    float s = 0.f;
    for (int j = tid; j < M; j += 256) {
        float pb = (float)hist[j] * (1.0f / (float)BNR);
        s += pb * logf(pb + 1e-10f);
    }
    red[tid] = s; __syncthreads();
    for (int o = 128; o > 0; o >>= 1) {
        if (tid < o) red[tid] += red[tid + o];
        __syncthreads();
    }
    if (tid == 0) out_perp[0] = expf(-red[0]);
}

extern "C" void kernel_launch(void* const* d_in, const int* in_sizes, int n_in,
                              void* d_out, int out_size, void* d_ws, size_t ws_size,
                              hipStream_t stream) {
    const float* x   = (const float*)d_in[0];
    const float* emb = (const float*)d_in[1];

    float* out        = (float*)d_out;
    float* out_zst    = out;                              // 8388608
    float* out_idx    = out + (size_t)BNR * C;            // 16384
    float* out_onehot = out_idx + BNR;                    // 134217728
    float* out_perp   = out_onehot + (size_t)BNR * M;     // 1

    // scratch lives in the onehot region (memset afterwards): ~41 MiB used
    u16*   x2t   = (u16*)out_onehot;                      // 16 MiB (tiled)
    u16*   e2t   = x2t + (size_t)BNR * C;                 // 8 MiB  (tiled)
    float* knorm = (float*)(e2t + (size_t)M * C);
    float* pv1   = knorm + M;                             // 4 MiB each
    float* pv2   = pv1 + (size_t)NSETS * BNR;
    int*   pi1   = (int*)(pv2 + (size_t)NSETS * BNR);
    int*   pi2   = pi1 + (size_t)NSETS * BNR;

    cvt_tile_k<<<(BNR * C / 8) / 256, 256, 0, stream>>>(x, x2t);
    cvt_tile_k<<<(M * C / 8) / 256, 256, 0, stream>>>(emb, e2t);
    knorm_k<<<64, 256, 0, stream>>>(emb, knorm);
    mfma_argmin_k<<<(BNR / BM) * (M / BN), 256, 0, stream>>>(
        x2t, e2t, knorm, pv1, pi1, pv2, pi2);
    refine_k<<<BNR / 4, 256, 0, stream>>>(x, emb, pv1, pi1, pv2, pi2, out_idx);

    hipMemsetAsync(out_onehot, 0, (size_t)BNR * M * sizeof(float), stream);
    gather_k<<<BNR, 128, 0, stream>>>(emb, out_idx, out_zst, out_onehot);
    perp_k<<<1, 256, 0, stream>>>(out_idx, out_perp);
}